// Round 12
// baseline (392.337 us; speedup 1.0000x reference)
//
#include <hip/hip_runtime.h>
#include <math.h>

// LDS geometry
#define GSTR 35            // gate-exchange px stride (floats; odd -> spread banks)
#define GPL  (64 * GSTR)   // one gate plane: 64 px x GSTR floats

typedef _Float16 half8 __attribute__((ext_vector_type(8)));
typedef float    f32x4 __attribute__((ext_vector_type(4)));

__device__ __forceinline__ float fast_tanh(float v) {
    float e = __expf(2.f * v);
    return 1.f - 2.f / (e + 1.f);
}
__device__ __forceinline__ float hsig(float v) {
    return fminf(fmaxf(0.2f * v + 0.5f, 0.f), 1.f);
}

// Pack weights: Wcx[tap][n][ci<32] from Wx[tap][ci][n]; Wch[tap][n][ci] from Wh[tap][ci][n]
__global__ void prep_w(const float* __restrict__ Wx, const float* __restrict__ Wh,
                       _Float16* __restrict__ Wcx, _Float16* __restrict__ Wch) {
    const int k = blockIdx.x;      // 0..575 = tap*64 + ci
    const int n = threadIdx.x;     // 0..127
    const int tap = k >> 6, ci = k & 63;
    if (ci < 32) Wcx[(tap * 128 + n) * 32 + ci]        = (_Float16)Wx[(tap * 32 + ci) * 128 + n];
    else         Wch[(tap * 128 + n) * 32 + (ci - 32)] = (_Float16)Wh[(tap * 32 + (ci - 32)) * 128 + n];
}

// One-shot parallel pass: x16 = (fp16)x, same [z][px][ch] layout. 32 MB, L3-resident.
__global__ __launch_bounds__(256)
void prep_x(const float* __restrict__ x, _Float16* __restrict__ x16) {
    const size_t i = ((size_t)blockIdx.x * 256 + threadIdx.x) * 8;   // 8 ch per thread
    const float4 v0 = *(const float4*)(x + i);
    const float4 v1 = *(const float4*)(x + i + 4);
    *(half8*)(x16 + i) = (half8){(_Float16)v0.x, (_Float16)v0.y, (_Float16)v0.z, (_Float16)v0.w,
                                 (_Float16)v1.x, (_Float16)v1.y, (_Float16)v1.z, (_Float16)v1.w};
}

// One fused timestep per launch — STAGE-FREE. A-fragments (16 B/lane, boundary-
// masked) are read directly from L2-resident x16 / hprev inside the tap loop,
// interleaved with MFMA (8 independent acc chains hide the L2 latency). Serial
// chain: launch -> {loads||MFMA} -> glds exchange -> barrier -> epilogue.
// N-split waves: wave w = gate w over all 64 px (4 m-tiles x 2 n-tiles).
// Grid (8,8,8): blockIdx.x = batch -> round-robin keeps batch b on XCD b, so
// hprev/c/x16 slices stay in that XCD's L2 across the 16 launches.
__global__ __launch_bounds__(256, 2)
void lstm_step_k(const _Float16* __restrict__ x16, const _Float16* __restrict__ Wcx,
                 const _Float16* __restrict__ Wch, const float* __restrict__ bias,
                 const float* __restrict__ gamma_, const float* __restrict__ beta_,
                 const float* __restrict__ mmean, const float* __restrict__ mvar,
                 const _Float16* __restrict__ hprev, _Float16* __restrict__ hnext,
                 float* __restrict__ csw, float* __restrict__ out, int t)
{
    __shared__ float glds[4 * GPL];       // 35.8 KB: gate exchange [gate][px][f]

    const int tid  = threadIdx.x;
    const int lane = tid & 63;
    const int w    = tid >> 6;            // wave index == gate (i,f,c,o)
    const int l15  = lane & 15, quad = lane >> 4;
    const int b = blockIdx.x, tx = blockIdx.y, ty = blockIdx.z;
    const int px0 = tx * 8, py0 = ty * 8;
    const int tile = ty * 8 + tx;

    // A-frag lane geometry: row p = mt*16 + l15 -> tile px (rowm[mt], c0)
    const int c0 = l15 & 7;
    int rowm[4];
    #pragma unroll
    for (int mt = 0; mt < 4; ++mt) rowm[mt] = mt * 2 + (l15 >> 3);

    const _Float16* xb = x16 + ((size_t)(b * 16 + t) * 4096) * 32;
    const _Float16* hb = hprev + (size_t)b * 4096 * 32;

    // ---- cell state: issue load early (consumed in epilogue) ----
    float* cp = csw + (((size_t)b * 64 + tile) * 256 + tid) * 8;
    float cov[8];
    #pragma unroll
    for (int j = 0; j < 8; ++j) cov[j] = 0.f;
    if (t > 0) {
        *(f32x4*)&cov[0] = *(const f32x4*)cp;
        *(f32x4*)&cov[4] = *(const f32x4*)(cp + 4);
    }

    // bias for this wave's gate: n = w*32 + ntl*16 + l15
    const float bi0 = bias[w * 32 + l15];
    const float bi1 = bias[w * 32 + 16 + l15];

    f32x4 acc[4][2];
    #pragma unroll
    for (int mt = 0; mt < 4; ++mt) {
        acc[mt][0] = (f32x4){bi0, bi0, bi0, bi0};
        acc[mt][1] = (f32x4){bi1, bi1, bi1, bi1};
    }

    const _Float16* wbx = Wcx + ((size_t)(w * 32 + l15)) * 32 + quad * 8;
    const _Float16* wbh = Wch + ((size_t)(w * 32 + l15)) * 32 + quad * 8;

    // ---- x-conv: A-frags direct from L2/L3 x16, interleaved with MFMA ----
    #pragma unroll
    for (int tap = 0; tap < 9; ++tap) {
        const int ky = tap / 3, kx = tap - ky * 3;
        const int gx = px0 + c0 + kx - 1;
        const bool vx = (unsigned)gx < 64u;
        half8 a[4];
        #pragma unroll
        for (int mt = 0; mt < 4; ++mt) {
            const int gy = py0 + rowm[mt] + ky - 1;
            a[mt] = (half8){0, 0, 0, 0, 0, 0, 0, 0};
            if (vx && (unsigned)gy < 64u)
                a[mt] = *(const half8*)(xb + ((size_t)(gy * 64 + gx)) * 32 + quad * 8);
        }
        #pragma unroll
        for (int ntl = 0; ntl < 2; ++ntl) {
            const half8 bf = *(const half8*)(wbx + tap * 4096 + ntl * 512);
            #pragma unroll
            for (int mt = 0; mt < 4; ++mt)
                acc[mt][ntl] = __builtin_amdgcn_mfma_f32_16x16x32_f16(a[mt], bf, acc[mt][ntl], 0, 0, 0);
        }
    }
    // ---- h-conv (skipped at t=0: h0 == 0), direct from L2 hprev ----
    if (t > 0) {
        #pragma unroll
        for (int tap = 0; tap < 9; ++tap) {
            const int ky = tap / 3, kx = tap - ky * 3;
            const int gx = px0 + c0 + kx - 1;
            const bool vx = (unsigned)gx < 64u;
            half8 a[4];
            #pragma unroll
            for (int mt = 0; mt < 4; ++mt) {
                const int gy = py0 + rowm[mt] + ky - 1;
                a[mt] = (half8){0, 0, 0, 0, 0, 0, 0, 0};
                if (vx && (unsigned)gy < 64u)
                    a[mt] = *(const half8*)(hb + ((size_t)(gy * 64 + gx)) * 32 + quad * 8);
            }
            #pragma unroll
            for (int ntl = 0; ntl < 2; ++ntl) {
                const half8 bf = *(const half8*)(wbh + tap * 4096 + ntl * 512);
                #pragma unroll
                for (int mt = 0; mt < 4; ++mt)
                    acc[mt][ntl] = __builtin_amdgcn_mfma_f32_16x16x32_f16(a[mt], bf, acc[mt][ntl], 0, 0, 0);
            }
        }
    }

    // ---- write this wave's gate plane to LDS: glds[w][px][f] ----
    #pragma unroll
    for (int mt = 0; mt < 4; ++mt)
        #pragma unroll
        for (int ntl = 0; ntl < 2; ++ntl)
            #pragma unroll
            for (int r = 0; r < 4; ++r) {
                const int px = mt * 16 + quad * 4 + r;
                glds[w * GPL + px * GSTR + ntl * 16 + l15] = acc[mt][ntl][r];
            }

    __syncthreads();

    // ---- epilogue: thread owns (px = tid>>2, f = f0..f0+7), coalesced I/O ----
    const int pxt = tid >> 2, f0 = (tid & 3) * 8;
    const int gy = py0 + (pxt >> 3), gx = px0 + (pxt & 7);

    float gav[8], bev[8], mmv[8], mvv[8];
    *(float4*)&gav[0] = *(const float4*)&gamma_[f0];
    *(float4*)&gav[4] = *(const float4*)&gamma_[f0 + 4];
    *(float4*)&bev[0] = *(const float4*)&beta_[f0];
    *(float4*)&bev[4] = *(const float4*)&beta_[f0 + 4];
    *(float4*)&mmv[0] = *(const float4*)&mmean[f0];
    *(float4*)&mmv[4] = *(const float4*)&mmean[f0 + 4];
    *(float4*)&mvv[0] = *(const float4*)&mvar[f0];
    *(float4*)&mvv[4] = *(const float4*)&mvar[f0 + 4];

    const int gb = pxt * GSTR + f0;
    half8 hv8;
    float ov[8], cnv[8];
    #pragma unroll
    for (int j = 0; j < 8; ++j) {
        const float gi = glds[0 * GPL + gb + j];
        const float gf = glds[1 * GPL + gb + j];
        const float gc = glds[2 * GPL + gb + j];
        const float go = glds[3 * GPL + gb + j];
        const float inv = gav[j] * rsqrtf(mvv[j] + 1e-3f);
        const float bnb = bev[j] - mmv[j] * inv;
        const float cn = hsig(gf) * cov[j] + hsig(gi) * fast_tanh(gc);
        const float hh = hsig(go) * fast_tanh(cn);
        cnv[j] = cn;
        hv8[j] = (_Float16)hh;
        ov[j] = hh * inv + bnb;
    }

    const size_t pix = ((size_t)(gy * 64 + gx)) * 32 + f0;
    float* oq = out + (((size_t)b * 16 + t) * 4096) * 32;
    *(float4*)(oq + pix)     = *(float4*)&ov[0];  // 2 x 16 B coalesced
    *(float4*)(oq + pix + 4) = *(float4*)&ov[4];
    if (t < 15) {                                  // h_15 / c_15 never consumed
        _Float16* hq = hnext + (size_t)b * 4096 * 32;
        *(half8*)(hq + pix) = hv8;                 // 16 B coalesced
        *(f32x4*)cp       = *(f32x4*)&cnv[0];      // 2 x 16 B coalesced
        *(f32x4*)(cp + 4) = *(f32x4*)&cnv[4];
    }
}

extern "C" void kernel_launch(void* const* d_in, const int* in_sizes, int n_in,
                              void* d_out, int out_size, void* d_ws, size_t ws_size,
                              hipStream_t stream)
{
    const float* x      = (const float*)d_in[0];
    const float* Wx     = (const float*)d_in[1];
    const float* Wh     = (const float*)d_in[2];
    const float* bias   = (const float*)d_in[3];
    const float* gamma_ = (const float*)d_in[4];
    const float* beta_  = (const float*)d_in[5];
    const float* mmean  = (const float*)d_in[6];
    const float* mvar   = (const float*)d_in[7];
    float* out = (float*)d_out;

    // ws: [h0 2MB][h1 2MB][csw 4MB][x16 32MB][Wcx 72KB][Wch 72KB]
    char* wsb = (char*)d_ws;
    _Float16* h0  = (_Float16*)(wsb);
    _Float16* h1  = (_Float16*)(wsb + (1 << 21));
    float*    csw = (float*)(wsb + (1 << 22));
    _Float16* x16 = (_Float16*)(wsb + (1 << 23));
    _Float16* Wcx = (_Float16*)(wsb + (1 << 23) + (1 << 25));
    _Float16* Wch = (_Float16*)(wsb + (1 << 23) + (1 << 25) + 73728);

    prep_w<<<dim3(576), dim3(128), 0, stream>>>(Wx, Wh, Wcx, Wch);
    // 16.7M halfs / (256 thr x 8) = 8192 blocks
    prep_x<<<dim3(8192), dim3(256), 0, stream>>>(x, x16);

    // 16 stage-free fused-step launches. No memset: t=0 skips h-conv and c-read.
    _Float16* hpr = h0;
    _Float16* hnx = h1;
    for (int t = 0; t < 16; ++t) {
        lstm_step_k<<<dim3(8, 8, 8), 256, 0, stream>>>(
            x16, Wcx, Wch, bias, gamma_, beta_, mmean, mvar, hpr, hnx, csw, out, t);
        _Float16* tmp = hpr; hpr = hnx; hnx = tmp;
    }
}